// Round 13
// baseline (151.873 us; speedup 1.0000x reference)
//
#include <hip/hip_runtime.h>
#include <hip/hip_bf16.h>

#define N_NODES 20000
#define N_EDGES 640000
#define HID 256
#define INDIM 128

// ---------- ws layout (bytes) ----------
#define WS_H_OFF    0u          // h fp8: 20000*256 = 5,120,000
#define WS_AGG_OFF  5120000u    // agg bf16: 10,240,000
#define WS_EW_OFF   15360000u   // emb_W bf16: 65,536
#define WS_MW_OFF   15425536u   // msg_W bf16: 131,072
#define WS_CS_OFF   15556608u   // colsum f32: 1024   (zeroed)
#define WS_DEG_OFF  15557632u   // deg: 80,000        (zeroed; countdown cursor)
#define WS_ROW_OFF  15637632u   // rowstart: 80,004 (+124 pad)
#define WS_SRC_OFF  15717760u   // srcs: 2,560,000
#define WS_NEEDED   18277760u

#define EW_ELEMS (HID * INDIM)              // 32,768
#define MW_ELEMS (HID * HID)                // 65,536
#define CONV_BLOCKS ((EW_ELEMS + MW_ELEMS) / 8 / 256)   // 48 exact
#define ZERO_BYTES  (1024 + 80000)          // colsum + deg, contiguous
#define ZERO_F4     (ZERO_BYTES / 16)       // 5064 exact
#define ZERO_BLOCKS ((ZERO_F4 + 255) / 256) // 20

#define EMB_BLOCKS  (N_NODES / 32)          // 625 exact (32-node tiles)
#define CNT_BLOCKS  (N_EDGES / 256)         // 2500 exact

typedef __attribute__((ext_vector_type(8))) short bf16x8;
typedef __attribute__((ext_vector_type(4))) float f32x4;
typedef __attribute__((ext_vector_type(2))) float f32x2;

__device__ inline unsigned short f2bf(float v) {
    union { float f; unsigned int u; } c; c.f = v;
    unsigned int lsb = (c.u >> 16) & 1u;
    c.u += 0x7fffu + lsb;                 // round-to-nearest-even
    return (unsigned short)(c.u >> 16);
}

// ---- fp8 e4m3fn (OCP), nonnegative inputs only (h is post-relu) ----------
__device__ inline unsigned char f2fp8(float v) {
    union { float f; unsigned int u; } c; c.f = v;
    if (v == 0.f) return 0;
    int e = (int)((c.u >> 23) & 0xff) - 127;
    if (e >= -6) {
        unsigned int mant = c.u & 0x7fffffu;
        unsigned int base = ((unsigned int)(e + 7) << 3) | (mant >> 20);
        unsigned int rem  = mant & 0xfffffu;
        base += (rem > 0x80000u) || (rem == 0x80000u && (base & 1u));
        return (unsigned char)base;
    } else {
        return (unsigned char)__builtin_rintf(v * 512.0f);   // denormal, exact
    }
}

// ---------------------------------------------------------------------------
// Convert emb_W, msg_W to bf16 (48 blocks); tail 20 blocks zero colsum+deg.
// ---------------------------------------------------------------------------
__global__ __launch_bounds__(256) void k_convert(const float* __restrict__ eW,
                                                 const float* __restrict__ mW,
                                                 unsigned short* __restrict__ eWbf,
                                                 unsigned short* __restrict__ mWbf,
                                                 float4* __restrict__ zbase)
{
    if (blockIdx.x >= CONV_BLOCKS) {
        const int zi = (blockIdx.x - CONV_BLOCKS) * 256 + threadIdx.x;
        if (zi < ZERO_F4) zbase[zi] = make_float4(0.f, 0.f, 0.f, 0.f);
        return;
    }
    const int t = blockIdx.x * 256 + threadIdx.x;
    const int i8 = t * 8;
    const float* src;
    unsigned short* dst;
    int off;
    if (i8 < EW_ELEMS) { src = eW; dst = eWbf; off = i8; }
    else               { src = mW; dst = mWbf; off = i8 - EW_ELEMS; }

    float4 a = *(const float4*)(src + off);
    float4 b = *(const float4*)(src + off + 4);
    unsigned short o[8] = { f2bf(a.x), f2bf(a.y), f2bf(a.z), f2bf(a.w),
                            f2bf(b.x), f2bf(b.y), f2bf(b.z), f2bf(b.w) };
    *(bf16x8*)(dst + off) = *(bf16x8*)o;
}

// ---------------------------------------------------------------------------
// MFMA embed, 32-node tiles (625 blocks -> 2.4 blocks/CU for latency hiding)
// + edge-degree count (blocks >= EMB_BLOCKS). A-frags packed in-register
// from f32 x. h stored fp8 e4m3 (5.1 MB -> L2-resident for gather).
// ---------------------------------------------------------------------------
__global__ __launch_bounds__(256) void k_embed_count(const float* __restrict__ x,
                                                     const unsigned short* __restrict__ Wbf,
                                                     const float* __restrict__ b,
                                                     unsigned char* __restrict__ h8,
                                                     const int* __restrict__ ei,
                                                     int* __restrict__ deg)
{
    if (blockIdx.x >= EMB_BLOCKS) {
        const int e = (blockIdx.x - EMB_BLOCKS) * 256 + threadIdx.x;
        if (e < N_EDGES) atomicAdd(&deg[ei[e]], 1);
        return;
    }

    const int tid  = threadIdx.x;
    const int wave = tid >> 6;
    const int lane = tid & 63;
    const int lr   = lane & 15;
    const int lq   = lane >> 4;
    const int n0   = blockIdx.x * 32;           // 20000 % 32 == 0: exact
    const int colbase = wave * 64;

    f32x4 acc[2][4] = {};

#pragma unroll
    for (int kk = 0; kk < INDIM; kk += 32) {
        bf16x8 a[2], bb[4];
#pragma unroll
        for (int g = 0; g < 2; ++g) {
            const float* xr = x + (size_t)(n0 + g * 16 + lr) * INDIM + kk + lq * 8;
            uint4 p0 = *(const uint4*)xr;
            uint4 p1 = *(const uint4*)(xr + 4);
            union { unsigned u[4]; bf16x8 v; } pk;
            pk.u[0] = ((p0.x + 0x8000u) >> 16) | ((p0.y + 0x8000u) & 0xFFFF0000u);
            pk.u[1] = ((p0.z + 0x8000u) >> 16) | ((p0.w + 0x8000u) & 0xFFFF0000u);
            pk.u[2] = ((p1.x + 0x8000u) >> 16) | ((p1.y + 0x8000u) & 0xFFFF0000u);
            pk.u[3] = ((p1.z + 0x8000u) >> 16) | ((p1.w + 0x8000u) & 0xFFFF0000u);
            a[g] = pk.v;
        }
#pragma unroll
        for (int c = 0; c < 4; ++c)
            bb[c] = *(const bf16x8*)(Wbf + (size_t)(colbase + c * 16 + lr) * INDIM + kk + lq * 8);
#pragma unroll
        for (int g = 0; g < 2; ++g)
#pragma unroll
            for (int c = 0; c < 4; ++c)
                acc[g][c] = __builtin_amdgcn_mfma_f32_16x16x32_bf16(a[g], bb[c], acc[g][c], 0, 0, 0);
    }

#pragma unroll
    for (int c = 0; c < 4; ++c) {
        const int j = colbase + c * 16 + lr;
        const float bias = b[j];
#pragma unroll
        for (int g = 0; g < 2; ++g) {
            const int nbase = n0 + g * 16 + lq * 4;
#pragma unroll
            for (int r = 0; r < 4; ++r) {
                const int n = nbase + r;
                float v = acc[g][c][r] + bias;
                v = v > 0.f ? v : 0.f;
                h8[(size_t)n * HID + j] = f2fp8(v);
            }
        }
    }
}

// ---------------------------------------------------------------------------
// Exclusive prefix sum of deg -> rowstart. Single block, shfl-based tree:
// 2 __syncthreads total (was 20 in the LDS ladder version).
// ---------------------------------------------------------------------------
__global__ __launch_bounds__(1024) void k_scan(const int* __restrict__ deg,
                                               int* __restrict__ rowstart)
{
    __shared__ int wsum[16];
    const int t  = threadIdx.x;
    const int wv = t >> 6;
    const int ln = t & 63;
    const int base = t * 20;                // 1024*20 = 20480 >= 20000

    int local[20];
    int s = 0;
#pragma unroll
    for (int i = 0; i < 20; ++i) {
        int idx = base + i;
        int v = (idx < N_NODES) ? deg[idx] : 0;
        local[i] = s;
        s += v;
    }

    // wave-level inclusive scan of per-thread sums
    int inc = s;
#pragma unroll
    for (int d = 1; d < 64; d <<= 1) {
        int u = __shfl_up(inc, d);
        if (ln >= d) inc += u;
    }
    if (ln == 63) wsum[wv] = inc;
    __syncthreads();

    // wave 0 scans the 16 wave totals (exclusive)
    if (wv == 0) {
        int v = (ln < 16) ? wsum[ln] : 0;
        int i2 = v;
#pragma unroll
        for (int d = 1; d < 16; d <<= 1) {
            int u = __shfl_up(i2, d);
            if (ln >= d) i2 += u;
        }
        if (ln < 16) wsum[ln] = i2 - v;
    }
    __syncthreads();

    const int pre = wsum[wv] + inc - s;     // exclusive prefix for this thread
#pragma unroll
    for (int i = 0; i < 20; ++i) {
        int idx = base + i;
        if (idx < N_NODES) rowstart[idx] = pre + local[i];
    }
    if (t == 1023) rowstart[N_NODES] = pre + s;
}

// deg[dst] still holds the count; consume it as a countdown cursor.
__global__ __launch_bounds__(256) void k_fill(const int* __restrict__ ei,
                                              const int* __restrict__ rowstart,
                                              int* __restrict__ deg,
                                              int* __restrict__ srcs)
{
    const int e = blockIdx.x * 256 + threadIdx.x;
    if (e >= N_EDGES) return;
    const int dst = ei[e];
    const int src = ei[N_EDGES + e];
    const int pos = rowstart[dst] + atomicSub(&deg[dst], 1) - 1;
    srcs[pos] = src;
}

// ---------------------------------------------------------------------------
// Gather: one wave per dst node; 16 lanes per edge, 16B/lane (uint4 = 1KB
// per instruction, 4 edges per load slot). Coalesced 64-wide srcs window,
// indices via shfl; cross-slot shfl_xor(16,32) fold. HW fp8 decode.
// ---------------------------------------------------------------------------
__global__ __launch_bounds__(256) void k_gather(const int* __restrict__ rowstart,
                                                const int* __restrict__ srcs,
                                                const unsigned char* __restrict__ h8,
                                                unsigned short* __restrict__ aggbf)
{
    const int wid  = (blockIdx.x * 256 + threadIdx.x) >> 6;  // node id
    const int lane = threadIdx.x & 63;
    if (wid >= N_NODES) return;

    const int s0 = rowstart[wid];
    const int s1 = rowstart[wid + 1];
    const int qslot = lane >> 4;          // which of 4 edges in a group
    const int coff  = lane & 15;          // 16B chunk within row

    float4 acc[4] = { {0,0,0,0}, {0,0,0,0}, {0,0,0,0}, {0,0,0,0} };

#define DEC(V)                                                            \
    {   f32x2 t_;                                                         \
        t_ = __builtin_amdgcn_cvt_pk_f32_fp8((V).x, false);               \
        acc[0].x += t_[0]; acc[0].y += t_[1];                             \
        t_ = __builtin_amdgcn_cvt_pk_f32_fp8((V).x, true);                \
        acc[0].z += t_[0]; acc[0].w += t_[1];                             \
        t_ = __builtin_amdgcn_cvt_pk_f32_fp8((V).y, false);               \
        acc[1].x += t_[0]; acc[1].y += t_[1];                             \
        t_ = __builtin_amdgcn_cvt_pk_f32_fp8((V).y, true);                \
        acc[1].z += t_[0]; acc[1].w += t_[1];                             \
        t_ = __builtin_amdgcn_cvt_pk_f32_fp8((V).z, false);               \
        acc[2].x += t_[0]; acc[2].y += t_[1];                             \
        t_ = __builtin_amdgcn_cvt_pk_f32_fp8((V).z, true);                \
        acc[2].z += t_[0]; acc[2].w += t_[1];                             \
        t_ = __builtin_amdgcn_cvt_pk_f32_fp8((V).w, false);               \
        acc[3].x += t_[0]; acc[3].y += t_[1];                             \
        t_ = __builtin_amdgcn_cvt_pk_f32_fp8((V).w, true);                \
        acc[3].z += t_[0]; acc[3].w += t_[1];  }

    for (int base = s0; base < s1; base += 64) {
        const int rem = s1 - base;
        const int cnt = rem < 64 ? rem : 64;
        const int idx = (lane < rem) ? srcs[base + lane] : 0;   // coalesced
        int k = 0;
        for (; k + 8 <= cnt; k += 8) {
            const int sA = __shfl(idx, k + qslot);
            const int sB = __shfl(idx, k + 4 + qslot);
            uint4 vA = *((const uint4*)(h8 + (size_t)sA * 256) + coff);
            uint4 vB = *((const uint4*)(h8 + (size_t)sB * 256) + coff);
            DEC(vA);
            DEC(vB);
        }
        for (; k < cnt; k += 4) {
            const int sA = __shfl(idx, k + qslot);
            uint4 v = *((const uint4*)(h8 + (size_t)sA * 256) + coff);
            if (k + qslot >= cnt) { v.x = 0; v.y = 0; v.z = 0; v.w = 0; }
            DEC(v);
        }
    }
#undef DEC

#pragma unroll
    for (int j = 0; j < 4; ++j) {
        acc[j].x += __shfl_xor(acc[j].x, 16);
        acc[j].y += __shfl_xor(acc[j].y, 16);
        acc[j].z += __shfl_xor(acc[j].z, 16);
        acc[j].w += __shfl_xor(acc[j].w, 16);
        acc[j].x += __shfl_xor(acc[j].x, 32);
        acc[j].y += __shfl_xor(acc[j].y, 32);
        acc[j].z += __shfl_xor(acc[j].z, 32);
        acc[j].w += __shfl_xor(acc[j].w, 32);
    }

    if (qslot == 0) {
        unsigned short o[16];
#pragma unroll
        for (int j = 0; j < 4; ++j) {
            o[j * 4 + 0] = f2bf(acc[j].x);
            o[j * 4 + 1] = f2bf(acc[j].y);
            o[j * 4 + 2] = f2bf(acc[j].z);
            o[j * 4 + 3] = f2bf(acc[j].w);
        }
        unsigned short* dst = aggbf + (size_t)wid * HID + coff * 16;
        *(bf16x8*)dst       = *(bf16x8*)o;
        *(bf16x8*)(dst + 8) = *(bf16x8*)(o + 8);
    }
}

// ---------------------------------------------------------------------------
// MFMA msg layer, 32-node tiles (625 blocks): h2 = relu(agg@msg_W.T+msg_b),
// column-summed into colsum without materializing h2.
// ---------------------------------------------------------------------------
__global__ __launch_bounds__(256) void k_msg_mfma(const unsigned short* __restrict__ aggbf,
                                                  const unsigned short* __restrict__ Wbf,
                                                  const float* __restrict__ b,
                                                  float* __restrict__ colsum)
{
    const int tid  = threadIdx.x;
    const int wave = tid >> 6;
    const int lane = tid & 63;
    const int lr   = lane & 15;
    const int lq   = lane >> 4;
    const int n0   = blockIdx.x * 32;           // exact: 20000 % 32 == 0
    const int colbase = wave * 64;

    f32x4 acc[2][4] = {};

#pragma unroll
    for (int kk = 0; kk < HID; kk += 32) {
        bf16x8 a[2], bb[4];
#pragma unroll
        for (int g = 0; g < 2; ++g)
            a[g] = *(const bf16x8*)(aggbf + (size_t)(n0 + g * 16 + lr) * HID + kk + lq * 8);
#pragma unroll
        for (int c = 0; c < 4; ++c)
            bb[c] = *(const bf16x8*)(Wbf + (size_t)(colbase + c * 16 + lr) * HID + kk + lq * 8);
#pragma unroll
        for (int g = 0; g < 2; ++g)
#pragma unroll
            for (int c = 0; c < 4; ++c)
                acc[g][c] = __builtin_amdgcn_mfma_f32_16x16x32_bf16(a[g], bb[c], acc[g][c], 0, 0, 0);
    }

#pragma unroll
    for (int c = 0; c < 4; ++c) {
        const int j = colbase + c * 16 + lr;
        const float bias = b[j];
        float part = 0.f;
#pragma unroll
        for (int g = 0; g < 2; ++g) {
#pragma unroll
            for (int r = 0; r < 4; ++r) {
                float v = acc[g][c][r] + bias;
                part += v > 0.f ? v : 0.f;
            }
        }
        part += __shfl_xor(part, 16);
        part += __shfl_xor(part, 32);
        if (lane < 16) unsafeAtomicAdd(&colsum[j], part);
    }
}

// ---------------------------------------------------------------------------
// Output matvecs from hmean = colsum / N.
// ---------------------------------------------------------------------------
__global__ __launch_bounds__(256) void k_out(const float* __restrict__ colsum,
                                             const float* __restrict__ W0,
                                             const float* __restrict__ b0,
                                             const float* __restrict__ W1,
                                             const float* __restrict__ b1,
                                             float* __restrict__ out)
{
    __shared__ float hm[HID];
    const int tid = threadIdx.x;
    hm[tid] = colsum[tid] * (1.0f / (float)N_NODES);
    __syncthreads();

    const int o = blockIdx.x * 256 + tid;
    const float* Wr;
    float bias;
    if (o < 8192) { Wr = W0 + (size_t)o * HID; bias = b0[o]; }
    else          { int o1 = o - 8192; Wr = W1 + (size_t)o1 * HID; bias = b1[o1]; }

    float s = bias;
    const float4* w4 = (const float4*)Wr;
    const float4* h4 = (const float4*)hm;
#pragma unroll 8
    for (int q = 0; q < 64; ++q) {
        float4 wv = w4[q];
        float4 hv = h4[q];
        s += wv.x * hv.x + wv.y * hv.y + wv.z * hv.z + wv.w * hv.w;
    }
    out[o] = s;
}

// ---------------------------------------------------------------------------
extern "C" void kernel_launch(void* const* d_in, const int* in_sizes, int n_in,
                              void* d_out, int out_size, void* d_ws, size_t ws_size,
                              hipStream_t stream)
{
    const float* x     = (const float*)d_in[0];
    const int*   ei    = (const int*)d_in[1];
    const float* emb_W = (const float*)d_in[2];
    const float* emb_b = (const float*)d_in[3];
    const float* msg_W = (const float*)d_in[4];
    const float* msg_b = (const float*)d_in[5];
    const float* W0    = (const float*)d_in[6];
    const float* b0    = (const float*)d_in[7];
    const float* W1    = (const float*)d_in[8];
    const float* b1    = (const float*)d_in[9];
    float* out = (float*)d_out;

    char* ws = (char*)d_ws;
    unsigned char*  h8    = (unsigned char*)(ws + WS_H_OFF);
    unsigned short* aggbf = (unsigned short*)(ws + WS_AGG_OFF);
    unsigned short* eWbf  = (unsigned short*)(ws + WS_EW_OFF);
    unsigned short* mWbf  = (unsigned short*)(ws + WS_MW_OFF);
    float* colsum = (float*)(ws + WS_CS_OFF);
    int* deg      = (int*)(ws + WS_DEG_OFF);
    int* rowstart = (int*)(ws + WS_ROW_OFF);
    int* srcs     = (int*)(ws + WS_SRC_OFF);

    // 1. convert weights to bf16 + zero colsum/deg
    k_convert<<<CONV_BLOCKS + ZERO_BLOCKS, 256, 0, stream>>>(
        emb_W, msg_W, eWbf, mWbf, (float4*)(ws + WS_CS_OFF));

    // 2. embed (MFMA, 32-node tiles) + degree count
    k_embed_count<<<EMB_BLOCKS + CNT_BLOCKS, 256, 0, stream>>>(
        x, eWbf, emb_b, h8, ei, deg);

    // 3-4. CSR scan + fill
    k_scan<<<1, 1024, 0, stream>>>(deg, rowstart);
    k_fill<<<CNT_BLOCKS, 256, 0, stream>>>(ei, rowstart, deg, srcs);

    // 5. gather (wave per node, 16 lanes/edge, HW fp8 decode)
    k_gather<<<(N_NODES * 64 + 255) / 256, 256, 0, stream>>>(rowstart, srcs, h8, aggbf);

    // 6. msg layer (32-node tiles) + column-sum
    k_msg_mfma<<<EMB_BLOCKS, 256, 0, stream>>>(aggbf, mWbf, msg_b, colsum);

    // 7. output matvecs
    k_out<<<(8192 + 2048) / 256, 256, 0, stream>>>(colsum, W0, b0, W1, b1, out);
}

// Round 14
// 138.010 us; speedup vs baseline: 1.1005x; 1.1005x over previous
//
#include <hip/hip_runtime.h>
#include <hip/hip_bf16.h>

#define N_NODES 20000
#define N_EDGES 640000
#define HID 256
#define INDIM 128

// ---------- ws layout (bytes) ----------
#define WS_H_OFF    0u          // h fp8: 20000*256 = 5,120,000
#define WS_AGG_OFF  5120000u    // agg bf16: 10,240,000
#define WS_EW_OFF   15360000u   // emb_W bf16: 65,536
#define WS_MW_OFF   15425536u   // msg_W bf16: 131,072
#define WS_CS_OFF   15556608u   // colsum f32: 1024   (zeroed)
#define WS_DEG_OFF  15557632u   // deg: 80,000        (zeroed; countdown cursor)
#define WS_ROW_OFF  15637632u   // rowstart: 80,004 (+124 pad)
#define WS_SRC_OFF  15717760u   // srcs: 2,560,000
#define WS_NEEDED   18277760u

#define EW_ELEMS (HID * INDIM)              // 32,768
#define MW_ELEMS (HID * HID)                // 65,536
#define CONV_BLOCKS ((EW_ELEMS + MW_ELEMS) / 8 / 256)   // 48 exact
#define ZERO_BYTES  (1024 + 80000)          // colsum + deg, contiguous
#define ZERO_F4     (ZERO_BYTES / 16)       // 5064 exact
#define ZERO_BLOCKS ((ZERO_F4 + 255) / 256) // 20

#define EMB_BLOCKS  ((N_NODES + 63) / 64)   // 313 (64-node tiles — R12 geometry)
#define CNT_BLOCKS  (N_EDGES / 256)         // 2500 exact

typedef __attribute__((ext_vector_type(8))) short bf16x8;
typedef __attribute__((ext_vector_type(4))) float f32x4;
typedef __attribute__((ext_vector_type(2))) float f32x2;

__device__ inline unsigned short f2bf(float v) {
    union { float f; unsigned int u; } c; c.f = v;
    unsigned int lsb = (c.u >> 16) & 1u;
    c.u += 0x7fffu + lsb;                 // round-to-nearest-even
    return (unsigned short)(c.u >> 16);
}

// ---- fp8 e4m3fn (OCP), nonnegative inputs only (h is post-relu) ----------
__device__ inline unsigned char f2fp8(float v) {
    union { float f; unsigned int u; } c; c.f = v;
    if (v == 0.f) return 0;
    int e = (int)((c.u >> 23) & 0xff) - 127;
    if (e >= -6) {
        unsigned int mant = c.u & 0x7fffffu;
        unsigned int base = ((unsigned int)(e + 7) << 3) | (mant >> 20);
        unsigned int rem  = mant & 0xfffffu;
        base += (rem > 0x80000u) || (rem == 0x80000u && (base & 1u));
        return (unsigned char)base;
    } else {
        return (unsigned char)__builtin_rintf(v * 512.0f);   // denormal, exact
    }
}

// ---------------------------------------------------------------------------
// Convert emb_W, msg_W to bf16 (48 blocks); tail 20 blocks zero colsum+deg.
// x is not staged: embed packs bf16 fragments from f32 in-register.
// ---------------------------------------------------------------------------
__global__ __launch_bounds__(256) void k_convert(const float* __restrict__ eW,
                                                 const float* __restrict__ mW,
                                                 unsigned short* __restrict__ eWbf,
                                                 unsigned short* __restrict__ mWbf,
                                                 float4* __restrict__ zbase)
{
    if (blockIdx.x >= CONV_BLOCKS) {
        const int zi = (blockIdx.x - CONV_BLOCKS) * 256 + threadIdx.x;
        if (zi < ZERO_F4) zbase[zi] = make_float4(0.f, 0.f, 0.f, 0.f);
        return;
    }
    const int t = blockIdx.x * 256 + threadIdx.x;
    const int i8 = t * 8;
    const float* src;
    unsigned short* dst;
    int off;
    if (i8 < EW_ELEMS) { src = eW; dst = eWbf; off = i8; }
    else               { src = mW; dst = mWbf; off = i8 - EW_ELEMS; }

    float4 a = *(const float4*)(src + off);
    float4 b = *(const float4*)(src + off + 4);
    unsigned short o[8] = { f2bf(a.x), f2bf(a.y), f2bf(a.z), f2bf(a.w),
                            f2bf(b.x), f2bf(b.y), f2bf(b.z), f2bf(b.w) };
    *(bf16x8*)(dst + off) = *(bf16x8*)o;
}

// ---------------------------------------------------------------------------
// MFMA embed (blocks < EMB_BLOCKS, 64-node tiles) + edge-degree count
// (blocks >= EMB_BLOCKS). A-frags packed in-register from f32 x.
// h stored fp8 e4m3 (5.1 MB -> L2-resident for gather).
// ---------------------------------------------------------------------------
__global__ __launch_bounds__(256) void k_embed_count(const float* __restrict__ x,
                                                     const unsigned short* __restrict__ Wbf,
                                                     const float* __restrict__ b,
                                                     unsigned char* __restrict__ h8,
                                                     const int* __restrict__ ei,
                                                     int* __restrict__ deg)
{
    if (blockIdx.x >= EMB_BLOCKS) {
        const int e = (blockIdx.x - EMB_BLOCKS) * 256 + threadIdx.x;
        if (e < N_EDGES) atomicAdd(&deg[ei[e]], 1);
        return;
    }

    const int tid  = threadIdx.x;
    const int wave = tid >> 6;
    const int lane = tid & 63;
    const int lr   = lane & 15;
    const int lq   = lane >> 4;
    const int n0   = blockIdx.x * 64;
    const int colbase = wave * 64;

    f32x4 acc[4][4] = {};

#pragma unroll
    for (int kk = 0; kk < INDIM; kk += 32) {
        bf16x8 a[4], bb[4];
#pragma unroll
        for (int g = 0; g < 4; ++g) {
            const float* xr = x + (size_t)(n0 + g * 16 + lr) * INDIM + kk + lq * 8;
            uint4 p0 = *(const uint4*)xr;
            uint4 p1 = *(const uint4*)(xr + 4);
            union { unsigned u[4]; bf16x8 v; } pk;
            pk.u[0] = ((p0.x + 0x8000u) >> 16) | ((p0.y + 0x8000u) & 0xFFFF0000u);
            pk.u[1] = ((p0.z + 0x8000u) >> 16) | ((p0.w + 0x8000u) & 0xFFFF0000u);
            pk.u[2] = ((p1.x + 0x8000u) >> 16) | ((p1.y + 0x8000u) & 0xFFFF0000u);
            pk.u[3] = ((p1.z + 0x8000u) >> 16) | ((p1.w + 0x8000u) & 0xFFFF0000u);
            a[g] = pk.v;
        }
#pragma unroll
        for (int c = 0; c < 4; ++c)
            bb[c] = *(const bf16x8*)(Wbf + (size_t)(colbase + c * 16 + lr) * INDIM + kk + lq * 8);
#pragma unroll
        for (int g = 0; g < 4; ++g)
#pragma unroll
            for (int c = 0; c < 4; ++c)
                acc[g][c] = __builtin_amdgcn_mfma_f32_16x16x32_bf16(a[g], bb[c], acc[g][c], 0, 0, 0);
    }

#pragma unroll
    for (int c = 0; c < 4; ++c) {
        const int j = colbase + c * 16 + lr;
        const float bias = b[j];
#pragma unroll
        for (int g = 0; g < 4; ++g) {
            const int nbase = n0 + g * 16 + lq * 4;
#pragma unroll
            for (int r = 0; r < 4; ++r) {
                const int n = nbase + r;
                if (n < N_NODES) {
                    float v = acc[g][c][r] + bias;
                    v = v > 0.f ? v : 0.f;
                    h8[(size_t)n * HID + j] = f2fp8(v);
                }
            }
        }
    }
}

// ---------------------------------------------------------------------------
// Exclusive prefix sum of deg -> rowstart. Single block, shfl-based tree:
// 2 __syncthreads total (validated in R13; the regression there was the
// tile change, not this).
// ---------------------------------------------------------------------------
__global__ __launch_bounds__(1024) void k_scan(const int* __restrict__ deg,
                                               int* __restrict__ rowstart)
{
    __shared__ int wsum[16];
    const int t  = threadIdx.x;
    const int wv = t >> 6;
    const int ln = t & 63;
    const int base = t * 20;                // 1024*20 = 20480 >= 20000

    int local[20];
    int s = 0;
#pragma unroll
    for (int i = 0; i < 20; ++i) {
        int idx = base + i;
        int v = (idx < N_NODES) ? deg[idx] : 0;
        local[i] = s;
        s += v;
    }

    // wave-level inclusive scan of per-thread sums
    int inc = s;
#pragma unroll
    for (int d = 1; d < 64; d <<= 1) {
        int u = __shfl_up(inc, d);
        if (ln >= d) inc += u;
    }
    if (ln == 63) wsum[wv] = inc;
    __syncthreads();

    // wave 0 scans the 16 wave totals (exclusive)
    if (wv == 0) {
        int v = (ln < 16) ? wsum[ln] : 0;
        int i2 = v;
#pragma unroll
        for (int d = 1; d < 16; d <<= 1) {
            int u = __shfl_up(i2, d);
            if (ln >= d) i2 += u;
        }
        if (ln < 16) wsum[ln] = i2 - v;
    }
    __syncthreads();

    const int pre = wsum[wv] + inc - s;     // exclusive prefix for this thread
#pragma unroll
    for (int i = 0; i < 20; ++i) {
        int idx = base + i;
        if (idx < N_NODES) rowstart[idx] = pre + local[i];
    }
    if (t == 1023) rowstart[N_NODES] = pre + s;
}

// deg[dst] still holds the count; consume it as a countdown cursor.
__global__ __launch_bounds__(256) void k_fill(const int* __restrict__ ei,
                                              const int* __restrict__ rowstart,
                                              int* __restrict__ deg,
                                              int* __restrict__ srcs)
{
    const int e = blockIdx.x * 256 + threadIdx.x;
    if (e >= N_EDGES) return;
    const int dst = ei[e];
    const int src = ei[N_EDGES + e];
    const int pos = rowstart[dst] + atomicSub(&deg[dst], 1) - 1;
    srcs[pos] = src;
}

// ---------------------------------------------------------------------------
// Gather: one wave per dst node; 16 lanes per edge, 16B/lane (uint4 = 1KB
// per instruction, 4 edges per load slot). Coalesced 64-wide srcs window,
// indices via shfl; cross-slot shfl_xor(16,32) fold. HW fp8 decode.
// ---------------------------------------------------------------------------
__global__ __launch_bounds__(256) void k_gather(const int* __restrict__ rowstart,
                                                const int* __restrict__ srcs,
                                                const unsigned char* __restrict__ h8,
                                                unsigned short* __restrict__ aggbf)
{
    const int wid  = (blockIdx.x * 256 + threadIdx.x) >> 6;  // node id
    const int lane = threadIdx.x & 63;
    if (wid >= N_NODES) return;

    const int s0 = rowstart[wid];
    const int s1 = rowstart[wid + 1];
    const int qslot = lane >> 4;          // which of 4 edges in a group
    const int coff  = lane & 15;          // 16B chunk within row

    float4 acc[4] = { {0,0,0,0}, {0,0,0,0}, {0,0,0,0}, {0,0,0,0} };

#define DEC(V)                                                            \
    {   f32x2 t_;                                                         \
        t_ = __builtin_amdgcn_cvt_pk_f32_fp8((V).x, false);               \
        acc[0].x += t_[0]; acc[0].y += t_[1];                             \
        t_ = __builtin_amdgcn_cvt_pk_f32_fp8((V).x, true);                \
        acc[0].z += t_[0]; acc[0].w += t_[1];                             \
        t_ = __builtin_amdgcn_cvt_pk_f32_fp8((V).y, false);               \
        acc[1].x += t_[0]; acc[1].y += t_[1];                             \
        t_ = __builtin_amdgcn_cvt_pk_f32_fp8((V).y, true);                \
        acc[1].z += t_[0]; acc[1].w += t_[1];                             \
        t_ = __builtin_amdgcn_cvt_pk_f32_fp8((V).z, false);               \
        acc[2].x += t_[0]; acc[2].y += t_[1];                             \
        t_ = __builtin_amdgcn_cvt_pk_f32_fp8((V).z, true);                \
        acc[2].z += t_[0]; acc[2].w += t_[1];                             \
        t_ = __builtin_amdgcn_cvt_pk_f32_fp8((V).w, false);               \
        acc[3].x += t_[0]; acc[3].y += t_[1];                             \
        t_ = __builtin_amdgcn_cvt_pk_f32_fp8((V).w, true);                \
        acc[3].z += t_[0]; acc[3].w += t_[1];  }

    for (int base = s0; base < s1; base += 64) {
        const int rem = s1 - base;
        const int cnt = rem < 64 ? rem : 64;
        const int idx = (lane < rem) ? srcs[base + lane] : 0;   // coalesced
        int k = 0;
        for (; k + 8 <= cnt; k += 8) {
            const int sA = __shfl(idx, k + qslot);
            const int sB = __shfl(idx, k + 4 + qslot);
            uint4 vA = *((const uint4*)(h8 + (size_t)sA * 256) + coff);
            uint4 vB = *((const uint4*)(h8 + (size_t)sB * 256) + coff);
            DEC(vA);
            DEC(vB);
        }
        for (; k < cnt; k += 4) {
            const int sA = __shfl(idx, k + qslot);
            uint4 v = *((const uint4*)(h8 + (size_t)sA * 256) + coff);
            if (k + qslot >= cnt) { v.x = 0; v.y = 0; v.z = 0; v.w = 0; }
            DEC(v);
        }
    }
#undef DEC

#pragma unroll
    for (int j = 0; j < 4; ++j) {
        acc[j].x += __shfl_xor(acc[j].x, 16);
        acc[j].y += __shfl_xor(acc[j].y, 16);
        acc[j].z += __shfl_xor(acc[j].z, 16);
        acc[j].w += __shfl_xor(acc[j].w, 16);
        acc[j].x += __shfl_xor(acc[j].x, 32);
        acc[j].y += __shfl_xor(acc[j].y, 32);
        acc[j].z += __shfl_xor(acc[j].z, 32);
        acc[j].w += __shfl_xor(acc[j].w, 32);
    }

    if (qslot == 0) {
        unsigned short o[16];
#pragma unroll
        for (int j = 0; j < 4; ++j) {
            o[j * 4 + 0] = f2bf(acc[j].x);
            o[j * 4 + 1] = f2bf(acc[j].y);
            o[j * 4 + 2] = f2bf(acc[j].z);
            o[j * 4 + 3] = f2bf(acc[j].w);
        }
        unsigned short* dst = aggbf + (size_t)wid * HID + coff * 16;
        *(bf16x8*)dst       = *(bf16x8*)o;
        *(bf16x8*)(dst + 8) = *(bf16x8*)(o + 8);
    }
}

// ---------------------------------------------------------------------------
// MFMA msg layer (64-node tiles): h2 = relu(agg @ msg_W.T + msg_b),
// column-summed into colsum without materializing h2.
// ---------------------------------------------------------------------------
__global__ __launch_bounds__(256) void k_msg_mfma(const unsigned short* __restrict__ aggbf,
                                                  const unsigned short* __restrict__ Wbf,
                                                  const float* __restrict__ b,
                                                  float* __restrict__ colsum)
{
    const int tid  = threadIdx.x;
    const int wave = tid >> 6;
    const int lane = tid & 63;
    const int lr   = lane & 15;
    const int lq   = lane >> 4;
    const int n0   = blockIdx.x * 64;
    const int colbase = wave * 64;

    f32x4 acc[4][4] = {};

#pragma unroll
    for (int kk = 0; kk < HID; kk += 32) {
        bf16x8 a[4], bb[4];
#pragma unroll
        for (int g = 0; g < 4; ++g)
            a[g] = *(const bf16x8*)(aggbf + (size_t)(n0 + g * 16 + lr) * HID + kk + lq * 8);
#pragma unroll
        for (int c = 0; c < 4; ++c)
            bb[c] = *(const bf16x8*)(Wbf + (size_t)(colbase + c * 16 + lr) * HID + kk + lq * 8);
#pragma unroll
        for (int g = 0; g < 4; ++g)
#pragma unroll
            for (int c = 0; c < 4; ++c)
                acc[g][c] = __builtin_amdgcn_mfma_f32_16x16x32_bf16(a[g], bb[c], acc[g][c], 0, 0, 0);
    }

#pragma unroll
    for (int c = 0; c < 4; ++c) {
        const int j = colbase + c * 16 + lr;
        const float bias = b[j];
        float part = 0.f;
#pragma unroll
        for (int g = 0; g < 4; ++g) {
            if (n0 + g * 16 < N_NODES) {      // 20000 % 16 == 0: exact cut
#pragma unroll
                for (int r = 0; r < 4; ++r) {
                    float v = acc[g][c][r] + bias;
                    part += v > 0.f ? v : 0.f;
                }
            }
        }
        part += __shfl_xor(part, 16);
        part += __shfl_xor(part, 32);
        if (lane < 16) unsafeAtomicAdd(&colsum[j], part);
    }
}

// ---------------------------------------------------------------------------
// Output matvecs from hmean = colsum / N.
// ---------------------------------------------------------------------------
__global__ __launch_bounds__(256) void k_out(const float* __restrict__ colsum,
                                             const float* __restrict__ W0,
                                             const float* __restrict__ b0,
                                             const float* __restrict__ W1,
                                             const float* __restrict__ b1,
                                             float* __restrict__ out)
{
    __shared__ float hm[HID];
    const int tid = threadIdx.x;
    hm[tid] = colsum[tid] * (1.0f / (float)N_NODES);
    __syncthreads();

    const int o = blockIdx.x * 256 + tid;
    const float* Wr;
    float bias;
    if (o < 8192) { Wr = W0 + (size_t)o * HID; bias = b0[o]; }
    else          { int o1 = o - 8192; Wr = W1 + (size_t)o1 * HID; bias = b1[o1]; }

    float s = bias;
    const float4* w4 = (const float4*)Wr;
    const float4* h4 = (const float4*)hm;
#pragma unroll 8
    for (int q = 0; q < 64; ++q) {
        float4 wv = w4[q];
        float4 hv = h4[q];
        s += wv.x * hv.x + wv.y * hv.y + wv.z * hv.z + wv.w * hv.w;
    }
    out[o] = s;
}

// ---------------------------------------------------------------------------
extern "C" void kernel_launch(void* const* d_in, const int* in_sizes, int n_in,
                              void* d_out, int out_size, void* d_ws, size_t ws_size,
                              hipStream_t stream)
{
    const float* x     = (const float*)d_in[0];
    const int*   ei    = (const int*)d_in[1];
    const float* emb_W = (const float*)d_in[2];
    const float* emb_b = (const float*)d_in[3];
    const float* msg_W = (const float*)d_in[4];
    const float* msg_b = (const float*)d_in[5];
    const float* W0    = (const float*)d_in[6];
    const float* b0    = (const float*)d_in[7];
    const float* W1    = (const float*)d_in[8];
    const float* b1    = (const float*)d_in[9];
    float* out = (float*)d_out;

    char* ws = (char*)d_ws;
    unsigned char*  h8    = (unsigned char*)(ws + WS_H_OFF);
    unsigned short* aggbf = (unsigned short*)(ws + WS_AGG_OFF);
    unsigned short* eWbf  = (unsigned short*)(ws + WS_EW_OFF);
    unsigned short* mWbf  = (unsigned short*)(ws + WS_MW_OFF);
    float* colsum = (float*)(ws + WS_CS_OFF);
    int* deg      = (int*)(ws + WS_DEG_OFF);
    int* rowstart = (int*)(ws + WS_ROW_OFF);
    int* srcs     = (int*)(ws + WS_SRC_OFF);

    // 1. convert weights to bf16 + zero colsum/deg
    k_convert<<<CONV_BLOCKS + ZERO_BLOCKS, 256, 0, stream>>>(
        emb_W, msg_W, eWbf, mWbf, (float4*)(ws + WS_CS_OFF));

    // 2. embed (MFMA, 64-node tiles, f32 x in-register packed) + degree count
    k_embed_count<<<EMB_BLOCKS + CNT_BLOCKS, 256, 0, stream>>>(
        x, eWbf, emb_b, h8, ei, deg);

    // 3-4. CSR scan + fill
    k_scan<<<1, 1024, 0, stream>>>(deg, rowstart);
    k_fill<<<CNT_BLOCKS, 256, 0, stream>>>(ei, rowstart, deg, srcs);

    // 5. gather (wave per node, 16 lanes/edge, HW fp8 decode)
    k_gather<<<(N_NODES * 64 + 255) / 256, 256, 0, stream>>>(rowstart, srcs, h8, aggbf);

    // 6. msg layer (64-node tiles) + column-sum
    k_msg_mfma<<<EMB_BLOCKS, 256, 0, stream>>>(aggbf, mWbf, msg_b, colsum);

    // 7. output matvecs
    k_out<<<(8192 + 2048) / 256, 256, 0, stream>>>(colsum, W0, b0, W1, b1, out);
}